// Round 1
// baseline (121.954 us; speedup 1.0000x reference)
//
#include <hip/hip_runtime.h>
#include <math.h>

// ---- problem geometry ----
#define T_IN    8192
#define T1      8183        // conv1 'valid' output length
#define T2      8174        // conv2 'valid' output length
#define LP      4087        // after MaxPool1d(2)
#define NFLAT   523136      // 128 * 4087
#define NDIM    10000
#define RSTRIDE 8208        // padded row stride for r1 (>= 8201, mult of 16)
#define F_OFF   (64*RSTRIDE)     // 525312 floats: start of flat[] in ws
#define P_OFF   (F_OFF + NFLAT)  // start of partials[128][32] in ws
#define NCHUNK  32
#define CHUNK   16348       // NFLAT/32 floats per chunk
#define CHUNK4  4087        // float4 per chunk

// =====================================================================
// Kernel 1: conv1 (in=4ch, out=64ch, k=10, VALID) + bias + ReLU
// r1 layout: [64][RSTRIDE] channel-major so conv2 can vector-load along t.
// grid (32 t-tiles, 4 c-groups), block 256. One thread = one t, 16 channels.
// =====================================================================
__global__ __launch_bounds__(256) void k1_conv1(
    const float* __restrict__ sig, const float* __restrict__ w1,
    const float* __restrict__ b1, float* __restrict__ r1)
{
  __shared__ float4 srow[266];               // rows t0b .. t0b+265 (4ch = float4)
  const int tid = threadIdx.x;
  const int t0b = blockIdx.x * 256;
  for (int idx = tid; idx < 266; idx += 256) {
    int t = t0b + idx;
    float4 v = make_float4(0.f, 0.f, 0.f, 0.f);
    if (t < T_IN) v = ((const float4*)sig)[t];
    srow[idx] = v;
  }
  __syncthreads();
  const int t = t0b + tid;
  float s[40];
#pragma unroll
  for (int k = 0; k < 10; ++k) {
    float4 v = srow[tid + k];
    s[4*k+0] = v.x; s[4*k+1] = v.y; s[4*k+2] = v.z; s[4*k+3] = v.w;
  }
  const int c0 = blockIdx.y * 16;
  for (int c = c0; c < c0 + 16; ++c) {
    const float* __restrict__ w = w1 + c * 40;   // [c][i][k], block-uniform -> s_load
    float a0 = 0.f, a1 = 0.f, a2 = 0.f, a3 = 0.f;
#pragma unroll
    for (int k = 0; k < 10; ++k) {
      a0 = fmaf(s[4*k+0], w[k     ], a0);
      a1 = fmaf(s[4*k+1], w[10 + k], a1);
      a2 = fmaf(s[4*k+2], w[20 + k], a2);
      a3 = fmaf(s[4*k+3], w[30 + k], a3);
    }
    float v = fmaxf((a0 + a1) + (a2 + a3) + b1[c], 0.f);
    if (t < T1) r1[c * RSTRIDE + t] = v;
  }
}

// =====================================================================
// Kernel 2: conv2 (64->128ch, k=10, VALID) + bias + ReLU + MaxPool(2)
// grid (32 t-tiles of 256, 8 o-tiles of 16), block 256 = 4 waves.
// Wave w owns channels o0..o0+3 (wave-uniform -> w2 via s_loads).
// Thread = lane, computes 4 consecutive t (2 pooled l) for its 4 channels.
// r1 staged through LDS in 16-channel chunks; consecutive-lane ds_read_b128.
// Writes flat[o*LP + l] (the reshape order the Linear expects).
// =====================================================================
__global__ __launch_bounds__(256) void k2_conv2pool(
    const float* __restrict__ r1, const float* __restrict__ w2,
    const float* __restrict__ b2, float* __restrict__ flat)
{
  __shared__ float tile[16][272];            // 16 channels x 272 floats (t0b..t0b+271)
  const int tid  = threadIdx.x;
  const int lane = tid & 63;
  const int wave = tid >> 6;
  const int t0b  = blockIdx.x * 256;
  const int o0   = __builtin_amdgcn_readfirstlane(blockIdx.y * 16 + wave * 4);
  const int t0   = t0b + lane * 4;

  float acc[4][4];
#pragma unroll
  for (int a = 0; a < 4; ++a)
#pragma unroll
    for (int b = 0; b < 4; ++b) acc[a][b] = 0.f;

  for (int cc = 0; cc < 4; ++cc) {
    __syncthreads();                          // protect previous chunk's reads
#pragma unroll
    for (int rr = 0; rr < 4; ++rr) {
      int row = wave * 4 + rr;
      const float4* src = (const float4*)(r1 + (cc * 16 + row) * RSTRIDE + t0b);
      ((float4*)&tile[row][0])[lane] = src[lane];
      if (lane < 4) ((float4*)&tile[row][0])[64 + lane] = src[64 + lane];
    }
    __syncthreads();

    for (int cr = 0; cr < 16; ++cr) {
      float f[16];
      const float4* tr4 = (const float4*)&tile[cr][0];
#pragma unroll
      for (int q = 0; q < 4; ++q) {
        float4 v = tr4[lane + q];             // floats lane*4+4q .. +3
        f[4*q+0] = v.x; f[4*q+1] = v.y; f[4*q+2] = v.z; f[4*q+3] = v.w;
      }
      const int c = cc * 16 + cr;
#pragma unroll
      for (int oo = 0; oo < 4; ++oo) {
        const float* __restrict__ w = w2 + ((o0 + oo) * 64 + c) * 10; // wave-uniform
#pragma unroll
        for (int k = 0; k < 10; ++k) {
          float wv = w[k];
#pragma unroll
          for (int tt = 0; tt < 4; ++tt)
            acc[oo][tt] = fmaf(wv, f[k + tt], acc[oo][tt]);
        }
      }
    }
  }

#pragma unroll
  for (int oo = 0; oo < 4; ++oo) {
    const int o = o0 + oo;
    const float bias = b2[o];
#pragma unroll
    for (int lt = 0; lt < 2; ++lt) {
      float a = acc[oo][2*lt]     + bias;
      float b = acc[oo][2*lt + 1] + bias;
      float m = fmaxf(fmaxf(a, b), 0.f);      // relu then pool == pool then relu
      int l = t0 / 2 + lt;
      if (l < LP) flat[o * LP + l] = m;
    }
  }
}

// =====================================================================
// Kernel 3: Linear partials. grid (32 f-chunks, 32 j-groups), block 256.
// Each block: 4 output rows x one 16348-float chunk, float4 streaming.
// Deterministic block-tree reduction -> partials[j][chunk] (no atomics).
// =====================================================================
__global__ __launch_bounds__(256) void k3_linear(
    const float* __restrict__ lw, const float* __restrict__ flat,
    float* __restrict__ partials)
{
  const int tid = threadIdx.x;
  const int ch  = blockIdx.x;        // 0..31
  const int j0  = blockIdx.y * 4;    // 0..124
  const float4* __restrict__ fl = (const float4*)(flat + ch * CHUNK);
  const float4* __restrict__ p0 = (const float4*)(lw + (size_t)(j0 + 0) * NFLAT + ch * CHUNK);
  const float4* __restrict__ p1 = (const float4*)(lw + (size_t)(j0 + 1) * NFLAT + ch * CHUNK);
  const float4* __restrict__ p2 = (const float4*)(lw + (size_t)(j0 + 2) * NFLAT + ch * CHUNK);
  const float4* __restrict__ p3 = (const float4*)(lw + (size_t)(j0 + 3) * NFLAT + ch * CHUNK);

  float4 a0 = make_float4(0,0,0,0), a1 = a0, a2 = a0, a3 = a0;
  for (int i = tid; i < CHUNK4; i += 256) {
    float4 x = fl[i];
    float4 w;
    w = p0[i]; a0.x = fmaf(x.x,w.x,a0.x); a0.y = fmaf(x.y,w.y,a0.y); a0.z = fmaf(x.z,w.z,a0.z); a0.w = fmaf(x.w,w.w,a0.w);
    w = p1[i]; a1.x = fmaf(x.x,w.x,a1.x); a1.y = fmaf(x.y,w.y,a1.y); a1.z = fmaf(x.z,w.z,a1.z); a1.w = fmaf(x.w,w.w,a1.w);
    w = p2[i]; a2.x = fmaf(x.x,w.x,a2.x); a2.y = fmaf(x.y,w.y,a2.y); a2.z = fmaf(x.z,w.z,a2.z); a2.w = fmaf(x.w,w.w,a2.w);
    w = p3[i]; a3.x = fmaf(x.x,w.x,a3.x); a3.y = fmaf(x.y,w.y,a3.y); a3.z = fmaf(x.z,w.z,a3.z); a3.w = fmaf(x.w,w.w,a3.w);
  }

  __shared__ float red[4][257];
  red[0][tid] = (a0.x + a0.y) + (a0.z + a0.w);
  red[1][tid] = (a1.x + a1.y) + (a1.z + a1.w);
  red[2][tid] = (a2.x + a2.y) + (a2.z + a2.w);
  red[3][tid] = (a3.x + a3.y) + (a3.z + a3.w);
  for (int off = 128; off > 0; off >>= 1) {
    __syncthreads();
    if (tid < off) {
#pragma unroll
      for (int j = 0; j < 4; ++j) red[j][tid] += red[j][tid + off];
    }
  }
  if (tid == 0) {
#pragma unroll
    for (int j = 0; j < 4; ++j) partials[(j0 + j) * NCHUNK + ch] = red[j][0];
  }
}

// =====================================================================
// Kernel 4: finalize. y = relu(lin_b + sum partials); proj = y . hdc_w[d];
// sample_hv, 18 feature sinusoids, combine, sign. grid 40 x 256 (d<10000).
// =====================================================================
__global__ __launch_bounds__(256) void k4_hdc(
    const float* __restrict__ partials, const float* __restrict__ lin_b,
    const float* __restrict__ hdc_w, const float* __restrict__ hdc_b,
    const float* __restrict__ feat, const int* __restrict__ feat_idx,
    const float* __restrict__ feat_w, const float* __restrict__ feat_b,
    float* __restrict__ out)
{
  __shared__ __align__(16) float y[128];
  __shared__ float fv[18];
  const int tid = threadIdx.x;
  if (tid < 128) {
    float s = lin_b[tid];
    const float* p = partials + tid * NCHUNK;
#pragma unroll
    for (int c = 0; c < NCHUNK; ++c) s += p[c];
    y[tid] = fmaxf(s, 0.f);
  }
  if (tid < 18) fv[tid] = feat[feat_idx[tid]];
  __syncthreads();

  const int d = blockIdx.x * 256 + tid;
  if (d >= NDIM) return;

  const float4* __restrict__ hw = (const float4*)(hdc_w + d * 128);
  const float4* __restrict__ yy = (const float4*)y;
  float4 ac = make_float4(0, 0, 0, 0);
#pragma unroll
  for (int q = 0; q < 32; ++q) {
    float4 w = hw[q];
    float4 v = yy[q];
    ac.x = fmaf(w.x, v.x, ac.x); ac.y = fmaf(w.y, v.y, ac.y);
    ac.z = fmaf(w.z, v.z, ac.z); ac.w = fmaf(w.w, v.w, ac.w);
  }
  const float proj = (ac.x + ac.y) + (ac.z + ac.w);
  const float sample_hv = cosf(proj + hdc_b[d]) * sinf(proj);

  float h[18];
#pragma unroll
  for (int i = 0; i < 18; ++i) {
    float fp = fv[i] * feat_w[i * NDIM + d];
    h[i] = cosf(fp + feat_b[i * NDIM + d]) * sinf(fp);
  }
  const float feat_hv =
      (h[14] + h[11]) * h[16]
    * (h[4] + h[8] + h[6] + h[1] + h[5] + h[12] + h[17])
    * h[13] * (h[15] + h[2]) * h[3]
    * h[0] * h[10] * h[7] * h[9];

  const float comb = sample_hv + feat_hv;
  out[d] = comb > 0.f ? 1.f : -1.f;
}

// =====================================================================
extern "C" void kernel_launch(void* const* d_in, const int* in_sizes, int n_in,
                              void* d_out, int out_size, void* d_ws, size_t ws_size,
                              hipStream_t stream)
{
  const float* sig  = (const float*)d_in[0];
  const float* feat = (const float*)d_in[1];
  const float* w1   = (const float*)d_in[2];
  const float* b1   = (const float*)d_in[3];
  const float* w2   = (const float*)d_in[4];
  const float* b2   = (const float*)d_in[5];
  const float* lw   = (const float*)d_in[6];
  const float* lb   = (const float*)d_in[7];
  const float* hw   = (const float*)d_in[8];
  const float* hb   = (const float*)d_in[9];
  const float* fw   = (const float*)d_in[10];
  const float* fb   = (const float*)d_in[11];
  const int*   fidx = (const int*)d_in[12];
  float* out = (float*)d_out;
  float* ws  = (float*)d_ws;

  float* r1       = ws;              // [64][RSTRIDE]
  float* flat     = ws + F_OFF;      // [NFLAT]
  float* partials = ws + P_OFF;      // [128][NCHUNK]

  k1_conv1   <<<dim3(32, 4),  256, 0, stream>>>(sig, w1, b1, r1);
  k2_conv2pool<<<dim3(32, 8), 256, 0, stream>>>(r1, w2, b2, flat);
  k3_linear  <<<dim3(32, 32), 256, 0, stream>>>(lw, flat, partials);
  k4_hdc     <<<dim3(40, 1),  256, 0, stream>>>(partials, lb, hw, hb,
                                                feat, fidx, fw, fb, out);
}

// Round 2
// 100.689 us; speedup vs baseline: 1.2112x; 1.2112x over previous
//
#include <hip/hip_runtime.h>
#include <math.h>

// ---- problem geometry ----
#define T_IN    8192
#define T1      8183        // conv1 'valid' output length
#define T2      8174        // conv2 'valid' output length
#define LP      4087        // after MaxPool1d(2)
#define NFLAT   523136      // 128 * 4087
#define NFLAT4  130784      // NFLAT / 4
#define NDIM    10000
#define RSTRIDE 8208        // padded row stride for r1 (>= 8201, mult of 16)
#define F_OFF   (64*RSTRIDE)     // start of flat[] in ws (floats)
#define P_OFF   (F_OFF + NFLAT)  // start of partials[128][32] in ws
#define NCHUNK  32
#define CHUNK4  4087        // float4 per chunk (NFLAT4 / 32)

typedef __attribute__((ext_vector_type(4))) float f4;

// =====================================================================
// Kernel 1: conv1 (in=4ch, out=64ch, k=10, VALID) + bias + ReLU
// r1 layout: [64][RSTRIDE] channel-major so conv2 can vector-load along t.
// grid (32 t-tiles, 8 c-groups), block 256. One thread = one t, 8 channels.
// =====================================================================
__global__ __launch_bounds__(256) void k1_conv1(
    const float* __restrict__ sig, const float* __restrict__ w1,
    const float* __restrict__ b1, float* __restrict__ r1)
{
  __shared__ float4 srow[266];               // rows t0b .. t0b+265 (4ch = float4)
  const int tid = threadIdx.x;
  const int t0b = blockIdx.x * 256;
  for (int idx = tid; idx < 266; idx += 256) {
    int t = t0b + idx;
    float4 v = make_float4(0.f, 0.f, 0.f, 0.f);
    if (t < T_IN) v = ((const float4*)sig)[t];
    srow[idx] = v;
  }
  __syncthreads();
  const int t = t0b + tid;
  float s[40];
#pragma unroll
  for (int k = 0; k < 10; ++k) {
    float4 v = srow[tid + k];
    s[4*k+0] = v.x; s[4*k+1] = v.y; s[4*k+2] = v.z; s[4*k+3] = v.w;
  }
  const int c0 = blockIdx.y * 8;
  for (int c = c0; c < c0 + 8; ++c) {
    const float* __restrict__ w = w1 + c * 40;   // block-uniform -> s_load
    float a0 = 0.f, a1 = 0.f, a2 = 0.f, a3 = 0.f;
#pragma unroll
    for (int k = 0; k < 10; ++k) {
      a0 = fmaf(s[4*k+0], w[k     ], a0);
      a1 = fmaf(s[4*k+1], w[10 + k], a1);
      a2 = fmaf(s[4*k+2], w[20 + k], a2);
      a3 = fmaf(s[4*k+3], w[30 + k], a3);
    }
    float v = fmaxf((a0 + a1) + (a2 + a3) + b1[c], 0.f);
    if (t < T1) r1[c * RSTRIDE + t] = v;
  }
}

// =====================================================================
// Kernel 2: conv2 (64->128ch, k=10, VALID) + bias + ReLU + MaxPool(2)
// grid (32 t-tiles of 256, 16 o-tiles of 8), block 256 = 4 waves.
// Wave w owns channels o0..o0+1 (wave-uniform -> w2 via s_loads).
// 512 blocks = 2/CU = 2 waves/SIMD (vs 1 last round) for latency hiding.
// Writes flat[o*LP + l] (the reshape order the Linear expects).
// =====================================================================
__global__ __launch_bounds__(256) void k2_conv2pool(
    const float* __restrict__ r1, const float* __restrict__ w2,
    const float* __restrict__ b2, float* __restrict__ flat)
{
  __shared__ float tile[16][272];            // 16 channels x floats t0b..t0b+271
  const int tid  = threadIdx.x;
  const int lane = tid & 63;
  const int wave = tid >> 6;
  const int t0b  = blockIdx.x * 256;
  const int o0   = __builtin_amdgcn_readfirstlane(blockIdx.y * 8 + wave * 2);
  const int t0   = t0b + lane * 4;

  float acc[2][4];
#pragma unroll
  for (int a = 0; a < 2; ++a)
#pragma unroll
    for (int b = 0; b < 4; ++b) acc[a][b] = 0.f;

  for (int cc = 0; cc < 4; ++cc) {
    __syncthreads();                          // protect previous chunk's reads
#pragma unroll
    for (int rr = 0; rr < 4; ++rr) {
      int row = wave * 4 + rr;
      const float4* src = (const float4*)(r1 + (cc * 16 + row) * RSTRIDE + t0b);
      ((float4*)&tile[row][0])[lane] = src[lane];
      if (lane < 4) ((float4*)&tile[row][0])[64 + lane] = src[64 + lane];
    }
    __syncthreads();

    for (int cr = 0; cr < 16; ++cr) {
      float f[16];
      const float4* tr4 = (const float4*)&tile[cr][0];
#pragma unroll
      for (int q = 0; q < 4; ++q) {
        float4 v = tr4[lane + q];             // floats lane*4+4q .. +3
        f[4*q+0] = v.x; f[4*q+1] = v.y; f[4*q+2] = v.z; f[4*q+3] = v.w;
      }
      const int c = cc * 16 + cr;
#pragma unroll
      for (int oo = 0; oo < 2; ++oo) {
        const float* __restrict__ w = w2 + ((o0 + oo) * 64 + c) * 10; // wave-uniform
#pragma unroll
        for (int k = 0; k < 10; ++k) {
          float wv = w[k];
#pragma unroll
          for (int tt = 0; tt < 4; ++tt)
            acc[oo][tt] = fmaf(wv, f[k + tt], acc[oo][tt]);
        }
      }
    }
  }

#pragma unroll
  for (int oo = 0; oo < 2; ++oo) {
    const int o = o0 + oo;
    const float bias = b2[o];
#pragma unroll
    for (int lt = 0; lt < 2; ++lt) {
      float a = acc[oo][2*lt]     + bias;
      float b = acc[oo][2*lt + 1] + bias;
      float m = fmaxf(fmaxf(a, b), 0.f);      // relu then pool == pool then relu
      int l = t0 / 2 + lt;
      if (l < LP) flat[o * LP + l] = m;
    }
  }
}

// =====================================================================
// Kernel 3: Linear partials. grid (32 f-chunks, 64 j-pairs) = 2048 blocks
// (8/CU). Each block: 2 output rows x one contiguous 65 KB weight chunk.
// Weights via nontemporal loads (zero reuse -> don't pollute L2/L3; flat
// stays cache-resident for its 64x re-read). Deterministic tree reduce.
// =====================================================================
__global__ __launch_bounds__(256) void k3_linear(
    const float* __restrict__ lw, const float* __restrict__ flat,
    float* __restrict__ partials)
{
  const int tid = threadIdx.x;
  const int ch  = blockIdx.x;        // 0..31
  const int j0  = blockIdx.y * 2;    // 0..126
  const f4* __restrict__ fl = (const f4*)flat + (size_t)ch * CHUNK4;
  const f4* __restrict__ p0 = (const f4*)lw + (size_t)(j0 + 0) * NFLAT4 + (size_t)ch * CHUNK4;
  const f4* __restrict__ p1 = (const f4*)lw + (size_t)(j0 + 1) * NFLAT4 + (size_t)ch * CHUNK4;

  f4 a0 = (f4)0.f, a1 = (f4)0.f;
  for (int i = tid; i < CHUNK4; i += 256) {
    f4 x  = fl[i];
    f4 w0 = __builtin_nontemporal_load(p0 + i);
    f4 w1 = __builtin_nontemporal_load(p1 + i);
    a0.x = fmaf(x.x, w0.x, a0.x); a0.y = fmaf(x.y, w0.y, a0.y);
    a0.z = fmaf(x.z, w0.z, a0.z); a0.w = fmaf(x.w, w0.w, a0.w);
    a1.x = fmaf(x.x, w1.x, a1.x); a1.y = fmaf(x.y, w1.y, a1.y);
    a1.z = fmaf(x.z, w1.z, a1.z); a1.w = fmaf(x.w, w1.w, a1.w);
  }

  __shared__ float red[2][257];
  red[0][tid] = (a0.x + a0.y) + (a0.z + a0.w);
  red[1][tid] = (a1.x + a1.y) + (a1.z + a1.w);
  for (int off = 128; off > 0; off >>= 1) {
    __syncthreads();
    if (tid < off) {
      red[0][tid] += red[0][tid + off];
      red[1][tid] += red[1][tid + off];
    }
  }
  if (tid == 0) {
    partials[(j0 + 0) * NCHUNK + ch] = red[0][0];
    partials[(j0 + 1) * NCHUNK + ch] = red[1][0];
  }
}

// =====================================================================
// Kernel 4: finalize. y = relu(lin_b + sum partials); proj = y . hdc_w[d];
// sample_hv, 18 feature sinusoids, combine, sign. grid 40 x 256 (d<10000).
// =====================================================================
__global__ __launch_bounds__(256) void k4_hdc(
    const float* __restrict__ partials, const float* __restrict__ lin_b,
    const float* __restrict__ hdc_w, const float* __restrict__ hdc_b,
    const float* __restrict__ feat, const int* __restrict__ feat_idx,
    const float* __restrict__ feat_w, const float* __restrict__ feat_b,
    float* __restrict__ out)
{
  __shared__ __align__(16) float y[128];
  __shared__ float fv[18];
  const int tid = threadIdx.x;
  if (tid < 128) {
    float s = lin_b[tid];
    const float* p = partials + tid * NCHUNK;
#pragma unroll
    for (int c = 0; c < NCHUNK; ++c) s += p[c];
    y[tid] = fmaxf(s, 0.f);
  }
  if (tid < 18) fv[tid] = feat[feat_idx[tid]];
  __syncthreads();

  const int d = blockIdx.x * 256 + tid;
  if (d >= NDIM) return;

  const float4* __restrict__ hw = (const float4*)(hdc_w + d * 128);
  const float4* __restrict__ yy = (const float4*)y;
  float4 ac = make_float4(0, 0, 0, 0);
#pragma unroll
  for (int q = 0; q < 32; ++q) {
    float4 w = hw[q];
    float4 v = yy[q];
    ac.x = fmaf(w.x, v.x, ac.x); ac.y = fmaf(w.y, v.y, ac.y);
    ac.z = fmaf(w.z, v.z, ac.z); ac.w = fmaf(w.w, v.w, ac.w);
  }
  const float proj = (ac.x + ac.y) + (ac.z + ac.w);
  const float sample_hv = cosf(proj + hdc_b[d]) * sinf(proj);

  float h[18];
#pragma unroll
  for (int i = 0; i < 18; ++i) {
    float fp = fv[i] * feat_w[i * NDIM + d];
    h[i] = cosf(fp + feat_b[i * NDIM + d]) * sinf(fp);
  }
  const float feat_hv =
      (h[14] + h[11]) * h[16]
    * (h[4] + h[8] + h[6] + h[1] + h[5] + h[12] + h[17])
    * h[13] * (h[15] + h[2]) * h[3]
    * h[0] * h[10] * h[7] * h[9];

  const float comb = sample_hv + feat_hv;
  out[d] = comb > 0.f ? 1.f : -1.f;
}

// =====================================================================
extern "C" void kernel_launch(void* const* d_in, const int* in_sizes, int n_in,
                              void* d_out, int out_size, void* d_ws, size_t ws_size,
                              hipStream_t stream)
{
  const float* sig  = (const float*)d_in[0];
  const float* feat = (const float*)d_in[1];
  const float* w1   = (const float*)d_in[2];
  const float* b1   = (const float*)d_in[3];
  const float* w2   = (const float*)d_in[4];
  const float* b2   = (const float*)d_in[5];
  const float* lw   = (const float*)d_in[6];
  const float* lb   = (const float*)d_in[7];
  const float* hw   = (const float*)d_in[8];
  const float* hb   = (const float*)d_in[9];
  const float* fw   = (const float*)d_in[10];
  const float* fb   = (const float*)d_in[11];
  const int*   fidx = (const int*)d_in[12];
  float* out = (float*)d_out;
  float* ws  = (float*)d_ws;

  float* r1       = ws;              // [64][RSTRIDE]
  float* flat     = ws + F_OFF;      // [NFLAT]
  float* partials = ws + P_OFF;      // [128][NCHUNK]

  k1_conv1    <<<dim3(32, 8),  256, 0, stream>>>(sig, w1, b1, r1);
  k2_conv2pool<<<dim3(32, 16), 256, 0, stream>>>(r1, w2, b2, flat);
  k3_linear   <<<dim3(32, 64), 256, 0, stream>>>(lw, flat, partials);
  k4_hdc      <<<dim3(40, 1),  256, 0, stream>>>(partials, lb, hw, hb,
                                                 feat, fidx, fw, fb, out);
}